// Round 2
// baseline (1244.137 us; speedup 1.0000x reference)
//
#include <hip/hip_runtime.h>
#include <hip/hip_bf16.h>
#include <stdint.h>

#define NNODES 50000
#define NEDGES 800000
#define DIN    2048
#define CDIM   256
#define ELOOP  (NEDGES + NNODES)   // edges + self loops

using bf16x8 = __attribute__((ext_vector_type(8))) short;
using f32x4  = __attribute__((ext_vector_type(4))) float;
using gvoid  = __attribute__((address_space(1))) const void;
using lvoid  = __attribute__((address_space(3))) void;

__device__ __forceinline__ float bf2f(uint16_t u) {
    union { uint32_t i; float f; } v; v.i = (uint32_t)u << 16; return v.f;
}
__device__ __forceinline__ uint16_t f2bf(float f) {
    union { float f; uint32_t i; } v; v.f = f;
    uint32_t i = v.i;
    return (uint16_t)((i + 0x7FFFu + ((i >> 16) & 1u)) >> 16);
}

#define BM 128
#define BN 128
#define BK 32

// ---------------------------------------------------------------- GEMM (bf16 A)
// C[M,N] = A[M,K] @ Bt[N,K]^T ; A,Bt,C bf16 row-major; bias fp32 optional.
__global__ __launch_bounds__(256)
void gemm_bt(const uint16_t* __restrict__ A, const uint16_t* __restrict__ Bt,
             uint16_t* __restrict__ C, const float* __restrict__ bias,
             int M, int N, int K)
{
    __shared__ __align__(16) uint16_t lA[BM * BK];   // 8 KB
    __shared__ __align__(16) uint16_t lB[BN * BK];   // 8 KB
    const int tid  = threadIdx.x;
    const int wave = tid >> 6;
    const int lane = tid & 63;
    const int lm = lane & 15, lq = lane >> 4;
    const int bm = blockIdx.x * BM;
    const int bn = blockIdx.y * BN;
    const int wm = (wave >> 1) * 64;
    const int wn = (wave & 1) * 64;

    f32x4 acc[4][4];
    for (int i = 0; i < 4; ++i)
        for (int j = 0; j < 4; ++j)
            acc[i][j] = (f32x4)0.0f;

    for (int k0 = 0; k0 < K; k0 += BK) {
        for (int j = 0; j < 2; ++j) {           // A tile: 512 x 16B chunks
            int c = j * 256 + wave * 64 + lane;
            int row = c >> 2, cc = c & 3;
            int gr = bm + row; if (gr >= M) gr = M - 1;
            const uint16_t* gp = A + (size_t)gr * K + k0 + cc * 8;
            __builtin_amdgcn_global_load_lds((gvoid*)gp,
                (lvoid*)(lA + (size_t)(j * 256 + wave * 64) * 8), 16, 0, 0);
        }
        for (int j = 0; j < 2; ++j) {           // B tile
            int c = j * 256 + wave * 64 + lane;
            int row = c >> 2, cc = c & 3;
            int gr = bn + row; if (gr >= N) gr = N - 1;
            const uint16_t* gp = Bt + (size_t)gr * K + k0 + cc * 8;
            __builtin_amdgcn_global_load_lds((gvoid*)gp,
                (lvoid*)(lB + (size_t)(j * 256 + wave * 64) * 8), 16, 0, 0);
        }
        __syncthreads();

        bf16x8 af[4], bfr[4];
        for (int mt = 0; mt < 4; ++mt)
            af[mt] = *(const bf16x8*)(lA + (wm + mt * 16 + lm) * BK + lq * 8);
        for (int nt = 0; nt < 4; ++nt)
            bfr[nt] = *(const bf16x8*)(lB + (wn + nt * 16 + lm) * BK + lq * 8);

        for (int mt = 0; mt < 4; ++mt)
            for (int nt = 0; nt < 4; ++nt)
                acc[mt][nt] = __builtin_amdgcn_mfma_f32_16x16x32_bf16(
                    af[mt], bfr[nt], acc[mt][nt], 0, 0, 0);
        __syncthreads();
    }

    for (int mt = 0; mt < 4; ++mt) {
        for (int nt = 0; nt < 4; ++nt) {
            int gn = bn + wn + nt * 16 + lm;
            float badd = bias ? bias[gn] : 0.0f;
            for (int r = 0; r < 4; ++r) {
                int gm = bm + wm + mt * 16 + lq * 4 + r;
                if (gm < M)
                    C[(size_t)gm * N + gn] = f2bf(acc[mt][nt][r] + badd);
            }
        }
    }
}

// ---------------------------------------------------------------- GEMM (fp32 A)
// C[M,N] = A_f32[M,K] @ Bt_bf16[N,K]^T ; converts A tiles fp32->bf16 at
// fragment read. A tile rows are 128 B (bank-period) -> XOR chunk swizzle.
__global__ __launch_bounds__(256)
void gemm_f32_bt(const float* __restrict__ A, const uint16_t* __restrict__ Bt,
                 uint16_t* __restrict__ C, int M, int N, int K)
{
    __shared__ __align__(16) float    lA[BM * BK];   // 16 KB fp32
    __shared__ __align__(16) uint16_t lB[BN * BK];   // 8 KB bf16
    const int tid  = threadIdx.x;
    const int wave = tid >> 6;
    const int lane = tid & 63;
    const int lm = lane & 15, lq = lane >> 4;
    const int bm = blockIdx.x * BM;
    const int bn = blockIdx.y * BN;
    const int wm = (wave >> 1) * 64;
    const int wn = (wave & 1) * 64;

    f32x4 acc[4][4];
    for (int i = 0; i < 4; ++i)
        for (int j = 0; j < 4; ++j)
            acc[i][j] = (f32x4)0.0f;

    for (int k0 = 0; k0 < K; k0 += BK) {
        // A tile fp32: 128 rows x 32 floats = 1024 x 16B chunks, XOR-swizzled
        for (int j = 0; j < 4; ++j) {
            int c = j * 256 + wave * 64 + lane;
            int row = c >> 3;                     // 8 chunks per row
            int lc  = (c & 7) ^ (row & 7);        // logical chunk in this slot
            int gr = bm + row; if (gr >= M) gr = M - 1;
            const float* gp = A + (size_t)gr * K + k0 + lc * 4;
            __builtin_amdgcn_global_load_lds((gvoid*)gp,
                (lvoid*)(lA + (size_t)(j * 256 + wave * 64) * 4), 16, 0, 0);
        }
        // B tile bf16: 512 x 16B chunks (m97 pattern, no swizzle)
        for (int j = 0; j < 2; ++j) {
            int c = j * 256 + wave * 64 + lane;
            int row = c >> 2, cc = c & 3;
            const uint16_t* gp = Bt + (size_t)(bn + row) * K + k0 + cc * 8;
            __builtin_amdgcn_global_load_lds((gvoid*)gp,
                (lvoid*)(lB + (size_t)(j * 256 + wave * 64) * 8), 16, 0, 0);
        }
        __syncthreads();

        bf16x8 af[4], bfr[4];
        for (int mt = 0; mt < 4; ++mt) {
            int r = wm + mt * 16 + lm;
            int s0 = (lq * 2)     ^ (r & 7);
            int s1 = (lq * 2 + 1) ^ (r & 7);
            f32x4 a0 = *(const f32x4*)(lA + r * BK + s0 * 4);
            f32x4 a1 = *(const f32x4*)(lA + r * BK + s1 * 4);
            bf16x8 t;
            for (int q = 0; q < 4; ++q) {
                t[q]     = (short)f2bf(a0[q]);
                t[q + 4] = (short)f2bf(a1[q]);
            }
            af[mt] = t;
        }
        for (int nt = 0; nt < 4; ++nt)
            bfr[nt] = *(const bf16x8*)(lB + (wn + nt * 16 + lm) * BK + lq * 8);

        for (int mt = 0; mt < 4; ++mt)
            for (int nt = 0; nt < 4; ++nt)
                acc[mt][nt] = __builtin_amdgcn_mfma_f32_16x16x32_bf16(
                    af[mt], bfr[nt], acc[mt][nt], 0, 0, 0);
        __syncthreads();
    }

    for (int mt = 0; mt < 4; ++mt) {
        for (int nt = 0; nt < 4; ++nt) {
            int gn = bn + wn + nt * 16 + lm;
            for (int r = 0; r < 4; ++r) {
                int gm = bm + wm + mt * 16 + lq * 4 + r;
                if (gm < M)
                    C[(size_t)gm * N + gn] = f2bf(acc[mt][nt][r]);
            }
        }
    }
}

// ---------------------------------------------------------------- weight prep
// Wt_bf16[n*K + k] = (bf16) W_f32[k*N + n]
__global__ void transpose_cvt_kernel(const float* __restrict__ W,
                                     uint16_t* __restrict__ Wt, int K, int N)
{
    int idx = blockIdx.x * 256 + threadIdx.x;
    if (idx >= K * N) return;
    int n = idx / K, k = idx - n * K;
    Wt[idx] = f2bf(W[(size_t)k * N + n]);
}

// ---------------------------------------------------------------- CSR build
__global__ void count_kernel(const int* __restrict__ ei, int* __restrict__ rs)
{
    int i = blockIdx.x * 256 + threadIdx.x;
    if (i >= ELOOP) return;
    int dst = (i < NEDGES) ? ei[NEDGES + i] : (i - NEDGES);
    atomicAdd(&rs[dst + 1], 1);
}

__global__ __launch_bounds__(1024)
void scan_kernel(int* __restrict__ rs, int* __restrict__ cursor)
{
    __shared__ int wsum[16];
    const int tid = threadIdx.x, lane = tid & 63, w = tid >> 6;
    int carry = 0;
    for (int base = 0; base <= NNODES; base += 1024) {
        int i = base + tid;
        int v = (i <= NNODES) ? rs[i] : 0;
        int s = v;
        for (int d = 1; d < 64; d <<= 1) {
            int t = __shfl_up(s, d);
            if (lane >= d) s += t;
        }
        if (lane == 63) wsum[w] = s;
        __syncthreads();
        if (tid < 16) {
            int x = wsum[tid];
            for (int d = 1; d < 16; d <<= 1) {
                int t = __shfl_up(x, d);
                if (tid >= d) x += t;
            }
            wsum[tid] = x;
        }
        __syncthreads();
        int incl = s + carry + (w > 0 ? wsum[w - 1] : 0);
        if (i <= NNODES) {
            rs[i] = incl;
            if (i < NNODES) cursor[i] = incl;
        }
        int total = carry + wsum[15];
        __syncthreads();
        carry = total;
    }
}

__global__ void fill_kernel(const int* __restrict__ ei, int* __restrict__ cursor,
                            int* __restrict__ csr_src)
{
    int i = blockIdx.x * 256 + threadIdx.x;
    if (i >= ELOOP) return;
    int src, dst;
    if (i < NEDGES) { src = ei[i]; dst = ei[NEDGES + i]; }
    else            { src = dst = i - NEDGES; }
    int pos = atomicAdd(&cursor[dst], 1);
    csr_src[pos] = src;
}

// ---------------------------------------------------------------- per-row dual dot
// s_src[n] = g[n,:]·a_src ; s_dst[n] = g[n,:]·a_dst  (g bf16, a fp32)
__global__ __launch_bounds__(256)
void rowdot_kernel(const uint16_t* __restrict__ g,
                   const float* __restrict__ asrc,
                   const float* __restrict__ adst,
                   float* __restrict__ s_src, float* __restrict__ s_dst)
{
    int n = blockIdx.x * 4 + (threadIdx.x >> 6);
    int lane = threadIdx.x & 63;
    ushort4 rv = *(const ushort4*)(g + (size_t)n * CDIM + lane * 4);
    float4 av = *(const float4*)(asrc + lane * 4);
    float4 dv = *(const float4*)(adst + lane * 4);
    float r0 = bf2f(rv.x), r1 = bf2f(rv.y), r2 = bf2f(rv.z), r3 = bf2f(rv.w);
    float a = r0 * av.x + r1 * av.y + r2 * av.z + r3 * av.w;
    float b = r0 * dv.x + r1 * dv.y + r2 * dv.z + r3 * dv.w;
    for (int d = 32; d; d >>= 1) { a += __shfl_xor(a, d); b += __shfl_xor(b, d); }
    if (lane == 0) { s_src[n] = a; s_dst[n] = b; }
}

// ---------------------------------------------------------------- GAT attention
__global__ __launch_bounds__(256)
void attn_kernel(const int* __restrict__ row_start, const int* __restrict__ csr_src,
                 const float* __restrict__ s_src, const float* __restrict__ s_dst,
                 const uint16_t* __restrict__ g, const float* __restrict__ bvec,
                 uint16_t* __restrict__ hout)
{
    int n = blockIdx.x * 4 + (threadIdx.x >> 6);
    int lane = threadIdx.x & 63;
    int beg = row_start[n], end = row_start[n + 1];
    float sdn = s_dst[n];

    float m = -1e30f;
    for (int i = beg + lane; i < end; i += 64) {
        float e = s_src[csr_src[i]] + sdn;
        e = (e > 0.f) ? e : 0.2f * e;
        m = fmaxf(m, e);
    }
    for (int d = 32; d; d >>= 1) m = fmaxf(m, __shfl_xor(m, d));

    float sum = 0.f;
    for (int i = beg + lane; i < end; i += 64) {
        float e = s_src[csr_src[i]] + sdn;
        e = (e > 0.f) ? e : 0.2f * e;
        sum += __expf(e - m);
    }
    for (int d = 32; d; d >>= 1) sum += __shfl_xor(sum, d);
    float inv = 1.f / (sum + 1e-16f);

    float a0 = 0.f, a1 = 0.f, a2 = 0.f, a3 = 0.f;
    for (int i = beg; i < end; ++i) {
        int src = csr_src[i];
        float e = s_src[src] + sdn;
        e = (e > 0.f) ? e : 0.2f * e;
        float alpha = __expf(e - m) * inv;
        ushort4 rv = *(const ushort4*)(g + (size_t)src * CDIM + lane * 4);
        a0 += alpha * bf2f(rv.x);
        a1 += alpha * bf2f(rv.y);
        a2 += alpha * bf2f(rv.z);
        a3 += alpha * bf2f(rv.w);
    }
    float4 bv = *(const float4*)(bvec + lane * 4);
    ushort4 o;
    o.x = f2bf(a0 + bv.x);
    o.y = f2bf(a1 + bv.y);
    o.z = f2bf(a2 + bv.z);
    o.w = f2bf(a3 + bv.w);
    *(ushort4*)(hout + (size_t)n * CDIM + lane * 4) = o;
}

// ---------------------------------------------------------------- edge predictor
// out[e] = relu(U[src]+V[dst]) · wp2 + bp2  (U has bp1 folded in; out fp32)
__global__ __launch_bounds__(256)
void edgepred_kernel(const int* __restrict__ ei,
                     const uint16_t* __restrict__ U, const uint16_t* __restrict__ V,
                     const float* __restrict__ wp2, const float* __restrict__ bp2,
                     float* __restrict__ out)
{
    const int tid = threadIdx.x;
    const int grp = tid >> 4, l = tid & 15;
    const int e = blockIdx.x * 16 + grp;
    int src = ei[e];
    int dst = ei[NEDGES + e];
    const uint4 u0 = *(const uint4*)(U + (size_t)src * CDIM + l * 16);
    const uint4 u1 = *(const uint4*)(U + (size_t)src * CDIM + l * 16 + 8);
    const uint4 v0 = *(const uint4*)(V + (size_t)dst * CDIM + l * 16);
    const uint4 v1 = *(const uint4*)(V + (size_t)dst * CDIM + l * 16 + 8);
    const float4 w0 = *(const float4*)(wp2 + l * 16);
    const float4 w1 = *(const float4*)(wp2 + l * 16 + 4);
    const float4 w2 = *(const float4*)(wp2 + l * 16 + 8);
    const float4 w3 = *(const float4*)(wp2 + l * 16 + 12);
    float acc = 0.f;
    auto proc = [&](uint32_t uu, uint32_t vv, float wa, float wb) {
        float z0 = fmaxf(bf2f((uint16_t)(uu & 0xffffu)) + bf2f((uint16_t)(vv & 0xffffu)), 0.f);
        float z1 = fmaxf(bf2f((uint16_t)(uu >> 16)) + bf2f((uint16_t)(vv >> 16)), 0.f);
        acc += z0 * wa + z1 * wb;
    };
    proc(u0.x, v0.x, w0.x, w0.y); proc(u0.y, v0.y, w0.z, w0.w);
    proc(u0.z, v0.z, w1.x, w1.y); proc(u0.w, v0.w, w1.z, w1.w);
    proc(u1.x, v1.x, w2.x, w2.y); proc(u1.y, v1.y, w2.z, w2.w);
    proc(u1.z, v1.z, w3.x, w3.y); proc(u1.w, v1.w, w3.z, w3.w);
    for (int d = 1; d < 16; d <<= 1) acc += __shfl_xor(acc, d);
    if (l == 0) out[e] = acc + *bp2;
}

// ---------------------------------------------------------------- launch
extern "C" void kernel_launch(void* const* d_in, const int* in_sizes, int n_in,
                              void* d_out, int out_size, void* d_ws, size_t ws_size,
                              hipStream_t stream)
{
    const float* x   = (const float*)d_in[0];
    const int*   ei  = (const int*)d_in[1];
    const float* W1  = (const float*)d_in[2];
    const float* as1 = (const float*)d_in[3];
    const float* ad1 = (const float*)d_in[4];
    const float* b1  = (const float*)d_in[5];
    const float* W2  = (const float*)d_in[6];
    const float* as2 = (const float*)d_in[7];
    const float* ad2 = (const float*)d_in[8];
    const float* b2  = (const float*)d_in[9];
    const float* Wp1 = (const float*)d_in[10];
    const float* bp1 = (const float*)d_in[11];
    const float* wp2 = (const float*)d_in[12];
    const float* bp2 = (const float*)d_in[13];
    float* out = (float*)d_out;

    char* ws = (char*)d_ws;
    size_t off = 0;
    auto alloc = [&](size_t bytes) -> void* {
        void* p = ws + off;
        off += (bytes + 255) & ~(size_t)255;
        return p;
    };
    uint16_t* W1t  = (uint16_t*)alloc((size_t)DIN * CDIM * 2);
    uint16_t* W2t  = (uint16_t*)alloc((size_t)CDIM * CDIM * 2);
    uint16_t* WpAt = (uint16_t*)alloc((size_t)CDIM * CDIM * 2);
    uint16_t* WpBt = (uint16_t*)alloc((size_t)CDIM * CDIM * 2);
    int* row_start = (int*)alloc((NNODES + 1) * sizeof(int));
    int* cursor    = (int*)alloc(NNODES * sizeof(int));
    int* csr_src   = (int*)alloc((size_t)ELOOP * sizeof(int));
    float* s_src   = (float*)alloc(NNODES * sizeof(float));
    float* s_dst   = (float*)alloc(NNODES * sizeof(float));
    uint16_t* G    = (uint16_t*)alloc((size_t)NNODES * CDIM * 2);  // lin out / U
    uint16_t* H    = (uint16_t*)alloc((size_t)NNODES * CDIM * 2);  // h1 / h2
    uint16_t* Vb   = (uint16_t*)alloc((size_t)NNODES * CDIM * 2);  // V

    hipMemsetAsync(row_start, 0, (NNODES + 1) * sizeof(int), stream);

    transpose_cvt_kernel<<<(DIN * CDIM + 255) / 256, 256, 0, stream>>>(W1, W1t, DIN, CDIM);
    transpose_cvt_kernel<<<(CDIM * CDIM + 255) / 256, 256, 0, stream>>>(W2, W2t, CDIM, CDIM);
    transpose_cvt_kernel<<<(CDIM * CDIM + 255) / 256, 256, 0, stream>>>(Wp1, WpAt, CDIM, CDIM);
    transpose_cvt_kernel<<<(CDIM * CDIM + 255) / 256, 256, 0, stream>>>(Wp1 + CDIM * CDIM, WpBt, CDIM, CDIM);

    count_kernel<<<(ELOOP + 255) / 256, 256, 0, stream>>>(ei, row_start);
    scan_kernel<<<1, 1024, 0, stream>>>(row_start, cursor);
    fill_kernel<<<(ELOOP + 255) / 256, 256, 0, stream>>>(ei, cursor, csr_src);

    dim3 gg((NNODES + BM - 1) / BM, CDIM / BN);

    // layer 1: h1_lin = x @ W1  (fp32 A path)
    gemm_f32_bt<<<gg, 256, 0, stream>>>(x, W1t, G, NNODES, CDIM, DIN);
    rowdot_kernel<<<NNODES / 4, 256, 0, stream>>>(G, as1, ad1, s_src, s_dst);
    attn_kernel<<<NNODES / 4, 256, 0, stream>>>(row_start, csr_src, s_src, s_dst, G, b1, H);

    // layer 2
    gemm_bt<<<gg, 256, 0, stream>>>(H, W2t, G, nullptr, NNODES, CDIM, CDIM);
    rowdot_kernel<<<NNODES / 4, 256, 0, stream>>>(G, as2, ad2, s_src, s_dst);
    attn_kernel<<<NNODES / 4, 256, 0, stream>>>(row_start, csr_src, s_src, s_dst, G, b2, H);

    // edge predictor: U = h2@Wp1_top + bp1 (into G), V = h2@Wp1_bot
    gemm_bt<<<gg, 256, 0, stream>>>(H, WpAt, G, bp1, NNODES, CDIM, CDIM);
    gemm_bt<<<gg, 256, 0, stream>>>(H, WpBt, Vb, nullptr, NNODES, CDIM, CDIM);

    edgepred_kernel<<<NEDGES / 16, 256, 0, stream>>>(ei, G, Vb, wp2, bp2, out);
}